// Round 22
// baseline (202.784 us; speedup 1.0000x reference)
//
#include <hip/hip_runtime.h>
#include <stdint.h>

#define S_LEN 4096
#define DMODEL 512
#define NHEAD 8
#define DK 64
#define SPLIT 8
#define TBLK 64
#define NT ((S_LEN / SPLIT) / TBLK)  // 8

#if __has_builtin(__builtin_amdgcn_exp2f)
#define EXPFN(x) __builtin_amdgcn_exp2f(x)
#define QSCALE 0.18033688011112042f  // 0.125 * log2(e): exp(S) = exp2(S')
#else
#define EXPFN(x) __expf(x)
#define QSCALE 0.125f
#endif

typedef __attribute__((ext_vector_type(8))) short short8;
typedef __attribute__((ext_vector_type(4))) float f32x4;
typedef __attribute__((ext_vector_type(16))) float f32x16;
typedef __attribute__((ext_vector_type(4))) unsigned int uint4v;

__device__ __forceinline__ unsigned short f2bf(float f) {
    unsigned int u = __float_as_uint(f);
    u = (u + 0x7fffu + ((u >> 16) & 1u)) >> 16;
    return (unsigned short)u;
}

// async global->LDS, 16B/lane; LDS dest = wave-uniform base + lane*16
__device__ __forceinline__ void gload16(const unsigned short* g, unsigned short* l) {
    __builtin_amdgcn_global_load_lds(
        (const __attribute__((address_space(1))) unsigned int*)g,
        (__attribute__((address_space(3))) unsigned int*)l, 16, 0, 0);
}

// ---------------- fused prep: cast emb + transpose qkv weights + transpose wo --
__global__ __launch_bounds__(256) void prep_kernel(
    const float* __restrict__ emb,
    const float* __restrict__ wq, const float* __restrict__ wk, const float* __restrict__ wv,
    const float* __restrict__ wo,
    unsigned short* __restrict__ embB,
    unsigned short* __restrict__ oq, unsigned short* __restrict__ ok,
    unsigned short* __restrict__ ov, unsigned short* __restrict__ woT,
    float* __restrict__ Z) {
    __shared__ float tile[64][65];
    const int blk = blockIdx.x, tid = threadIdx.x;
    if (blk < 2048) {  // cast emb f32 -> bf16, + zero Z
        int i = blk * 256 + tid;
        if (i == 0) *Z = 0.0f;
        float4 v = reinterpret_cast<const float4*>(emb)[i];
        ushort4 o;
        o.x = f2bf(v.x); o.y = f2bf(v.y); o.z = f2bf(v.z); o.w = f2bf(v.w);
        reinterpret_cast<ushort4*>(embB)[i] = o;
        return;
    }
    const int tr = tid >> 4, tc4 = (tid & 15) * 4;
    if (blk < 2240) {  // qkv: [h][512][64] -> [h][64][512]
        int idx = blk - 2048;
        int xx = idx & 7, yy = idx >> 3;
        int p = yy >> 3, h = yy & 7;
        const float* in = ((p == 0) ? wq : (p == 1) ? wk : wv) + (size_t)h * DMODEL * DK;
        unsigned short* out = ((p == 0) ? oq : (p == 1) ? ok : ov) + (size_t)h * DK * DMODEL;
        int r0 = xx * 64;
#pragma unroll
        for (int rr = 0; rr < 4; ++rr) {
            float4 v = *reinterpret_cast<const float4*>(in + (size_t)(r0 + tr + rr * 16) * DK + tc4);
            tile[tr + rr * 16][tc4 + 0] = v.x;
            tile[tr + rr * 16][tc4 + 1] = v.y;
            tile[tr + rr * 16][tc4 + 2] = v.z;
            tile[tr + rr * 16][tc4 + 3] = v.w;
        }
        __syncthreads();
#pragma unroll
        for (int rr = 0; rr < 4; ++rr) {
            const int c = tr + rr * 16;
            ushort4 o;
            o.x = f2bf(tile[tc4 + 0][c]);
            o.y = f2bf(tile[tc4 + 1][c]);
            o.z = f2bf(tile[tc4 + 2][c]);
            o.w = f2bf(tile[tc4 + 3][c]);
            *reinterpret_cast<ushort4*>(out + (size_t)c * DMODEL + r0 + tc4) = o;
        }
        return;
    }
    {  // wo: [512][512] -> transposed
        int idx = blk - 2240;
        int c0 = (idx & 7) * 64, r0 = (idx >> 3) * 64;
#pragma unroll
        for (int rr = 0; rr < 4; ++rr) {
            float4 v = *reinterpret_cast<const float4*>(wo + (size_t)(r0 + tr + rr * 16) * DMODEL + c0 + tc4);
            tile[tr + rr * 16][tc4 + 0] = v.x;
            tile[tr + rr * 16][tc4 + 1] = v.y;
            tile[tr + rr * 16][tc4 + 2] = v.z;
            tile[tr + rr * 16][tc4 + 3] = v.w;
        }
        __syncthreads();
#pragma unroll
        for (int rr = 0; rr < 4; ++rr) {
            const int c = tr + rr * 16;
            ushort4 o;
            o.x = f2bf(tile[tc4 + 0][c]);
            o.y = f2bf(tile[tc4 + 1][c]);
            o.z = f2bf(tile[tc4 + 2][c]);
            o.w = f2bf(tile[tc4 + 3][c]);
            *reinterpret_cast<ushort4*>(woT + (size_t)(c0 + c) * DMODEL + r0 + tc4) = o;
        }
    }
}

// ---------------- tiled QKV projection GEMM (m97 structure) ----------------
__global__ __launch_bounds__(256, 2) void proj_tiled_kernel(
    const unsigned short* __restrict__ A,
    const unsigned short* __restrict__ BTall,
    unsigned short* __restrict__ Qo,
    unsigned short* __restrict__ Ko,
    unsigned short* __restrict__ Vo) {
    __shared__ unsigned short lds[32768];
    const int tid = threadIdx.x;
    const int w = tid >> 6, l = tid & 63;
    const int l15 = l & 15, lg = l >> 4;
    const int wr = w >> 1, wc = w & 1;
    const int m0 = blockIdx.x * 128, n0 = blockIdx.y * 128;
    const int srow = l >> 3;
    const int schk = ((l & 7) ^ srow) << 3;
    f32x4 acc[4][4] = {};
    {
        unsigned short* ab = &lds[0];
        unsigned short* bb = &lds[8192];
#pragma unroll
        for (int g = 0; g < 4; ++g) {
            gload16(A + (size_t)(m0 + w * 32 + g * 8 + srow) * DMODEL + schk,
                    ab + (w * 32 + g * 8) * 64);
            gload16(BTall + (size_t)(n0 + w * 32 + g * 8 + srow) * DMODEL + schk,
                    bb + (w * 32 + g * 8) * 64);
        }
    }
    __syncthreads();
    for (int kt = 0; kt < 8; ++kt) {
        const int b = (kt & 1) * 16384;
        if (kt + 1 < 8) {
            const int nb = ((kt + 1) & 1) * 16384;
            const int k0 = (kt + 1) * 64;
            unsigned short* ab = &lds[nb];
            unsigned short* bb = &lds[nb + 8192];
#pragma unroll
            for (int g = 0; g < 4; ++g) {
                gload16(A + (size_t)(m0 + w * 32 + g * 8 + srow) * DMODEL + k0 + schk,
                        ab + (w * 32 + g * 8) * 64);
                gload16(BTall + (size_t)(n0 + w * 32 + g * 8 + srow) * DMODEL + k0 + schk,
                        bb + (w * 32 + g * 8) * 64);
            }
        }
#pragma unroll
        for (int kk = 0; kk < 2; ++kk) {
            short8 am[4], bn[4];
#pragma unroll
            for (int mi = 0; mi < 4; ++mi) {
                const int row = wr * 64 + mi * 16 + l15;
                am[mi] = *reinterpret_cast<const short8*>(
                    &lds[b + row * 64 + ((kk * 32 + lg * 8) ^ ((row & 7) << 3))]);
            }
#pragma unroll
            for (int ni = 0; ni < 4; ++ni) {
                const int row = wc * 64 + ni * 16 + l15;
                bn[ni] = *reinterpret_cast<const short8*>(
                    &lds[b + 8192 + row * 64 + ((kk * 32 + lg * 8) ^ ((row & 7) << 3))]);
            }
#pragma unroll
            for (int mi = 0; mi < 4; ++mi)
#pragma unroll
                for (int ni = 0; ni < 4; ++ni)
                    acc[mi][ni] = __builtin_amdgcn_mfma_f32_16x16x32_bf16(am[mi], bn[ni], acc[mi][ni], 0, 0, 0);
        }
        __syncthreads();
    }
#pragma unroll
    for (int ni = 0; ni < 4; ++ni) {
        const int n = n0 + wc * 64 + ni * 16;
        const int p = n >> 9, h = (n >> 6) & 7, vb = n & 63;
        unsigned short* dst = ((p == 0) ? Qo : (p == 1) ? Ko : Vo) + (size_t)h * S_LEN * DK;
        const float sc = (p == 0) ? QSCALE : 1.0f;
#pragma unroll
        for (int mi = 0; mi < 4; ++mi) {
            const int s = m0 + wr * 64 + mi * 16 + lg * 4;
#pragma unroll
            for (int r = 0; r < 4; ++r)
                dst[(size_t)(s + r) * DK + vb + l15] = f2bf(acc[mi][ni][r] * sc);
        }
    }
}

// ---------------- V transpose + k-permute: Vb[h][t][v] -> VTp[h][v][t'] -----
__global__ __launch_bounds__(256) void vt_kernel(const unsigned short* __restrict__ Vb,
                                                 unsigned short* __restrict__ VT) {
    __shared__ unsigned short tile[4096];
    int h = blockIdx.y, t0 = blockIdx.x * 64;
    const unsigned short* Vh = Vb + h * (S_LEN * DK);
    unsigned short* VTh = VT + h * (DK * S_LEN);
    int c8 = (threadIdx.x & 7) * 8, rw = threadIdx.x >> 3;
#pragma unroll
    for (int rr = 0; rr < 2; ++rr) {
        int t = rw + rr * 32;
        short8 v = *reinterpret_cast<const short8*>(Vh + (t0 + t) * DK + c8);
        *reinterpret_cast<short8*>(&tile[t * 64 + (c8 ^ ((t & 7) << 3))]) = v;
    }
    __syncthreads();
    const int g16 = c8 & ~15;
    const int h4 = (c8 & 8) ? 4 : 0;
#pragma unroll
    for (int rr = 0; rr < 2; ++rr) {
        int v = rw + rr * 32;
        short8 s;
#pragma unroll
        for (int i = 0; i < 8; ++i) {
            int t = g16 + h4 + ((i < 4) ? i : (i + 4));  // k-permuted source
            s[i] = (short)tile[t * 64 + (v ^ ((t & 7) << 3))];
        }
        *reinterpret_cast<short8*>(VTh + v * S_LEN + t0 + c8) = s;
    }
}

// ---------------- fused attention (unnormalized, split over t) ----------------
// r18 per-wave body VERBATIM; block geometry changed: 8 waves x 64 q = 512 q
// per block sharing ONE K/VT tile (staging-per-FLOP halves), SPLIT=8 ->
// 512 blocks x 512 thr = 2 blocks/CU = 16 waves/CU (2x r18). VGPR ~100
// under the (512,4) cap of 128.
__device__ __forceinline__ void make_pfrag(const f32x16& s, short8 pf[2],
                                           float& z0, float& z1) {
    float p[16];
#pragma unroll
    for (int r = 0; r < 16; ++r) p[r] = EXPFN(s[r]);
#pragma unroll
    for (int r = 0; r < 16; r += 2) { z0 += p[r]; z1 += p[r + 1]; }
    unsigned int c[8];
#pragma unroll
    for (int j = 0; j < 8; ++j)
        asm("v_cvt_pk_bf16_f32 %0, %1, %2" : "=v"(c[j]) : "v"(p[2 * j]), "v"(p[2 * j + 1]));
    uint4v wa = {c[0], c[1], c[2], c[3]};
    uint4v wb = {c[4], c[5], c[6], c[7]};
    pf[0] = __builtin_bit_cast(short8, wa);
    pf[1] = __builtin_bit_cast(short8, wb);
}

__global__ __launch_bounds__(512, 4) void attn_kernel(
    const unsigned short* __restrict__ Qg,
    const unsigned short* __restrict__ Kg,
    const unsigned short* __restrict__ VTg,
    unsigned short* __restrict__ Opart,
    float* __restrict__ Z) {
    __shared__ unsigned short lds[16384];  // 2 bufs x (K[64][64] + VT[64][64]) = 32KB
    const int tid = threadIdx.x;
    const int w = tid >> 6, l = tid & 63;   // 8 waves
    const int l31 = l & 31, lh = l >> 5;
    const int vx = l31 & 7;
    const int qb = blockIdx.x, h = blockIdx.y, sp = blockIdx.z;
    const unsigned short* Qh = Qg + h * (S_LEN * DK);
    const unsigned short* Kh = Kg + h * (S_LEN * DK);
    const unsigned short* VTh = VTg + h * (DK * S_LEN);
    const int t_base = sp * (S_LEN / SPLIT);
    const int q0 = qb * 512 + w * 64;  // 8 waves x 64 q

    short8 bq[2][4];
#pragma unroll
    for (int qc = 0; qc < 2; ++qc)
#pragma unroll
        for (int ks = 0; ks < 4; ++ks)
            bq[qc][ks] = *reinterpret_cast<const short8*>(
                Qh + (q0 + qc * 32 + l31) * DK + ks * 16 + lh * 8);

    f32x16 oacc[2][2] = {};  // [qc][vc]
    float z0 = 0.0f, z1 = 0.0f;

    // staging: wave w covers 8 rows of K and 8 rows of VT (1 gload16 each)
    const int srow = l >> 3;
    const int scol = ((l & 7) ^ srow) << 3;
    const unsigned short* gk = Kh + (size_t)(t_base + w * 8 + srow) * DK + scol;
    const unsigned short* gv = VTh + (size_t)(w * 8 + srow) * S_LEN + t_base + scol;

    {   // stage tile 0 -> buf 0
        gload16(gk, &lds[w * 512]);
        gload16(gv, &lds[4096 + w * 512]);
        gk += 64 * DK; gv += 64;
    }
    __syncthreads();

    for (int it = 0; it < NT; ++it) {
        const int b = (it & 1) * 8192;
        if (it + 1 < NT) {  // async loads into other buf; drain at loop-end barrier
            const int nb = ((it + 1) & 1) * 8192;
            gload16(gk, &lds[nb + w * 512]);
            gload16(gv, &lds[nb + 4096 + w * 512]);
            gk += 64 * DK; gv += 64;
        }
#pragma unroll
        for (int tc = 0; tc < 2; ++tc) {
            f32x16 s0 = {}, s1 = {};
            const int tA = tc * 32 + l31;
            __builtin_amdgcn_s_setprio(1);
#pragma unroll
            for (int ks = 0; ks < 4; ++ks) {
                short8 ka = *reinterpret_cast<const short8*>(
                    &lds[b + tA * 64 + ((ks * 16 + lh * 8) ^ ((tA & 7) << 3))]);
                s0 = __builtin_amdgcn_mfma_f32_32x32x16_bf16(ka, bq[0][ks], s0, 0, 0, 0);
                s1 = __builtin_amdgcn_mfma_f32_32x32x16_bf16(ka, bq[1][ks], s1, 0, 0, 0);
            }
            __builtin_amdgcn_s_setprio(0);
            // hoist PV B-frag reads (independent of exp): latency hides under exp
            short8 bv[2][2];
#pragma unroll
            for (int sub = 0; sub < 2; ++sub) {
                const int chk = (tc * 2 + sub) * 2 + lh;
#pragma unroll
                for (int vc = 0; vc < 2; ++vc) {
                    const int v = vc * 32 + l31;
                    bv[sub][vc] = *reinterpret_cast<const short8*>(
                        &lds[b + 4096 + v * 64 + ((chk ^ vx) << 3)]);
                }
            }
            // interleave: pfrag(s0) -> PV(qc0) while pfrag(s1) runs -> PV(qc1)
            short8 pf0[2], pf1[2];
            make_pfrag(s0, pf0, z0, z1);
#pragma unroll
            for (int sub = 0; sub < 2; ++sub)
#pragma unroll
                for (int vc = 0; vc < 2; ++vc)
                    oacc[0][vc] = __builtin_amdgcn_mfma_f32_32x32x16_bf16(pf0[sub], bv[sub][vc], oacc[0][vc], 0, 0, 0);
            make_pfrag(s1, pf1, z0, z1);
            __builtin_amdgcn_s_setprio(1);
#pragma unroll
            for (int sub = 0; sub < 2; ++sub)
#pragma unroll
                for (int vc = 0; vc < 2; ++vc)
                    oacc[1][vc] = __builtin_amdgcn_mfma_f32_32x32x16_bf16(pf1[sub], bv[sub][vc], oacc[1][vc], 0, 0, 0);
            __builtin_amdgcn_s_setprio(0);
        }
        __syncthreads();
    }
    // bf16 partials: Opart[sp][h][q][v], coalesced (lanes = consecutive v)
    unsigned short* Op = Opart + ((size_t)(sp * NHEAD + h) * S_LEN + q0) * DK;
#pragma unroll
    for (int qc = 0; qc < 2; ++qc)
#pragma unroll
        for (int vc = 0; vc < 2; ++vc)
#pragma unroll
            for (int reg = 0; reg < 16; ++reg) {
                int q = qc * 32 + (reg & 3) + 8 * (reg >> 2) + 4 * lh;
                Op[(size_t)q * DK + vc * 32 + l31] = f2bf(oacc[qc][vc][reg]);
            }
    float zloc = z0 + z1;
#pragma unroll
    for (int off = 32; off > 0; off >>= 1) zloc += __shfl_xor(zloc, off, 64);
    if (l == 0) atomicAdd(Z, zloc);
}

// ---------------- split reduction: sum bf16 partials -> bf16 concat ----------------
__global__ __launch_bounds__(256) void reduce_o_kernel(
    const unsigned short* __restrict__ Opart, unsigned short* __restrict__ cc) {
    const int HSV = NHEAD * S_LEN * DK;
    int i = blockIdx.x * blockDim.x + threadIdx.x;
    if (i * 4 >= HSV) return;
    float s0 = 0, s1 = 0, s2 = 0, s3 = 0;
#pragma unroll
    for (int sp = 0; sp < SPLIT; ++sp) {
        ushort4 v = *reinterpret_cast<const ushort4*>(&Opart[(size_t)sp * HSV + i * 4]);
        s0 += __uint_as_float((unsigned int)v.x << 16);
        s1 += __uint_as_float((unsigned int)v.y << 16);
        s2 += __uint_as_float((unsigned int)v.z << 16);
        s3 += __uint_as_float((unsigned int)v.w << 16);
    }
    int e = i * 4;
    int h = e / (S_LEN * DK);
    int rem = e - h * (S_LEN * DK);
    int srow = rem / DK;
    int v = rem - srow * DK;
    ushort4 o4;
    o4.x = f2bf(s0); o4.y = f2bf(s1); o4.z = f2bf(s2); o4.w = f2bf(s3);
    *reinterpret_cast<ushort4*>(&cc[srow * DMODEL + h * DK + v]) = o4;
}

// ---------------- tiled output projection GEMM (x 1/Z) ----------------
__global__ __launch_bounds__(256, 2) void out_tiled_kernel(
    const unsigned short* __restrict__ A,
    const unsigned short* __restrict__ BT,
    const float* __restrict__ Z,
    float* __restrict__ Cout) {
    __shared__ unsigned short lds[32768];
    const int tid = threadIdx.x;
    const int w = tid >> 6, l = tid & 63;
    const int l15 = l & 15, lg = l >> 4;
    const int wr = w >> 1, wc = w & 1;
    const int m0 = blockIdx.x * 128, n0 = blockIdx.y * 128;
    const int srow = l >> 3;
    const int schk = ((l & 7) ^ srow) << 3;
    const float invZ = 1.0f / *Z;
    f32x4 acc[4][4] = {};
    {
        unsigned short* ab = &lds[0];
        unsigned short* bb = &lds[8192];
#pragma unroll
        for (int g = 0; g < 4; ++g) {
            gload16(A + (size_t)(m0 + w * 32 + g * 8 + srow) * DMODEL + schk,
                    ab + (w * 32 + g * 8) * 64);
            gload16(BT + (size_t)(n0 + w * 32 + g * 8 + srow) * DMODEL + schk,
                    bb + (w * 32 + g * 8) * 64);
        }
    }
    __syncthreads();
    for (int kt = 0; kt < 8; ++kt) {
        const int b = (kt & 1) * 16384;
        if (kt + 1 < 8) {
            const int nb = ((kt + 1) & 1) * 16384;
            const int k0 = (kt + 1) * 64;
            unsigned short* ab = &lds[nb];
            unsigned short* bb = &lds[nb + 8192];
#pragma unroll
            for (int g = 0; g < 4; ++g) {
                gload16(A + (size_t)(m0 + w * 32 + g * 8 + srow) * DMODEL + k0 + schk,
                        ab + (w * 32 + g * 8) * 64);
                gload16(BT + (size_t)(n0 + w * 32 + g * 8 + srow) * DMODEL + k0 + schk,
                        bb + (w * 32 + g * 8) * 64);
            }
        }
#pragma unroll
        for (int kk = 0; kk < 2; ++kk) {
            short8 am[4], bn[4];
#pragma unroll
            for (int mi = 0; mi < 4; ++mi) {
                const int row = wr * 64 + mi * 16 + l15;
                am[mi] = *reinterpret_cast<const short8*>(
                    &lds[b + row * 64 + ((kk * 32 + lg * 8) ^ ((row & 7) << 3))]);
            }
#pragma unroll
            for (int ni = 0; ni < 4; ++ni) {
                const int row = wc * 64 + ni * 16 + l15;
                bn[ni] = *reinterpret_cast<const short8*>(
                    &lds[b + 8192 + row * 64 + ((kk * 32 + lg * 8) ^ ((row & 7) << 3))]);
            }
#pragma unroll
            for (int mi = 0; mi < 4; ++mi)
#pragma unroll
                for (int ni = 0; ni < 4; ++ni)
                    acc[mi][ni] = __builtin_amdgcn_mfma_f32_16x16x32_bf16(am[mi], bn[ni], acc[mi][ni], 0, 0, 0);
        }
        __syncthreads();
    }
#pragma unroll
    for (int ni = 0; ni < 4; ++ni) {
        const int n = n0 + wc * 64 + ni * 16;
#pragma unroll
        for (int mi = 0; mi < 4; ++mi) {
            const int s = m0 + wr * 64 + mi * 16 + lg * 4;
#pragma unroll
            for (int r = 0; r < 4; ++r)
                Cout[(size_t)(s + r) * DMODEL + n + l15] = acc[mi][ni][r] * invZ;
        }
    }
}

// ---------------- launcher ----------------

extern "C" void kernel_launch(void* const* d_in, const int* in_sizes, int n_in,
                              void* d_out, int out_size, void* d_ws, size_t ws_size,
                              hipStream_t stream) {
    const float* emb = (const float*)d_in[0];
    const float* wq = (const float*)d_in[1];
    const float* wk = (const float*)d_in[2];
    const float* wv = (const float*)d_in[3];
    const float* wo = (const float*)d_in[4];
    float* out = (float*)d_out;
    char* ws = (char*)d_ws;
    unsigned short* embB = (unsigned short*)(ws);             // 4 MB (reused as VT)
    unsigned short* wqT  = (unsigned short*)(ws + 4194304);   // contiguous 3 x 512 KB
    unsigned short* wkT  = (unsigned short*)(ws + 4718592);
    unsigned short* wvT  = (unsigned short*)(ws + 5242880);
    unsigned short* woT  = (unsigned short*)(ws + 5767168);
    unsigned short* Qb   = (unsigned short*)(ws + 6291456);   // 4 MB each
    unsigned short* Kb   = (unsigned short*)(ws + 10485760);
    unsigned short* Vb   = (unsigned short*)(ws + 14680064);
    unsigned short* cc   = (unsigned short*)(ws + 18874368);  // 4 MB
    float* Z             = (float*)(ws + 23068672);
    unsigned short* Opart = (unsigned short*)(ws + 23072768); // 32 MB (8 x 4 MB bf16)
    unsigned short* VT   = embB;  // embB dead after proj

    prep_kernel<<<2304, 256, 0, stream>>>(emb, wq, wk, wv, wo, embB, wqT, wkT, wvT, woT, Z);
    proj_tiled_kernel<<<dim3(32, 12), 256, 0, stream>>>(embB, wqT, Qb, Kb, Vb);
    vt_kernel<<<dim3(64, 8), 256, 0, stream>>>(Vb, VT);
    attn_kernel<<<dim3(8, 8, SPLIT), 512, 0, stream>>>(Qb, Kb, VT, Opart, Z);
    reduce_o_kernel<<<2048, 256, 0, stream>>>(Opart, cc);
    out_tiled_kernel<<<dim3(32, 4), 256, 0, stream>>>(cc, woT, Z, out);
}

// Round 23
// 91.830 us; speedup vs baseline: 2.2083x; 2.2083x over previous
//
#include <hip/hip_runtime.h>
#include <stdint.h>

#define S_LEN 4096
#define DMODEL 512
#define NHEAD 8
#define DK 64
#define SPLIT 4
#define TBLK 64
#define NT ((S_LEN / SPLIT) / TBLK)  // 16

#if __has_builtin(__builtin_amdgcn_exp2f)
#define EXPFN(x) __builtin_amdgcn_exp2f(x)
#define QSCALE 0.18033688011112042f  // 0.125 * log2(e): exp(S) = exp2(S')
#else
#define EXPFN(x) __expf(x)
#define QSCALE 0.125f
#endif

typedef __attribute__((ext_vector_type(8))) short short8;
typedef __attribute__((ext_vector_type(4))) float f32x4;
typedef __attribute__((ext_vector_type(16))) float f32x16;
typedef __attribute__((ext_vector_type(4))) unsigned int uint4v;

__device__ __forceinline__ unsigned short f2bf(float f) {
    unsigned int u = __float_as_uint(f);
    u = (u + 0x7fffu + ((u >> 16) & 1u)) >> 16;
    return (unsigned short)u;
}

// async global->LDS, 16B/lane; LDS dest = wave-uniform base + lane*16
__device__ __forceinline__ void gload16(const unsigned short* g, unsigned short* l) {
    __builtin_amdgcn_global_load_lds(
        (const __attribute__((address_space(1))) unsigned int*)g,
        (__attribute__((address_space(3))) unsigned int*)l, 16, 0, 0);
}

// ---------------- fused prep: cast emb + transpose qkv weights + transpose wo --
__global__ __launch_bounds__(256) void prep_kernel(
    const float* __restrict__ emb,
    const float* __restrict__ wq, const float* __restrict__ wk, const float* __restrict__ wv,
    const float* __restrict__ wo,
    unsigned short* __restrict__ embB,
    unsigned short* __restrict__ oq, unsigned short* __restrict__ ok,
    unsigned short* __restrict__ ov, unsigned short* __restrict__ woT,
    float* __restrict__ Z) {
    __shared__ float tile[64][65];
    const int blk = blockIdx.x, tid = threadIdx.x;
    if (blk < 2048) {  // cast emb f32 -> bf16, + zero Z
        int i = blk * 256 + tid;
        if (i == 0) *Z = 0.0f;
        float4 v = reinterpret_cast<const float4*>(emb)[i];
        ushort4 o;
        o.x = f2bf(v.x); o.y = f2bf(v.y); o.z = f2bf(v.z); o.w = f2bf(v.w);
        reinterpret_cast<ushort4*>(embB)[i] = o;
        return;
    }
    const int tr = tid >> 4, tc4 = (tid & 15) * 4;
    if (blk < 2240) {  // qkv: [h][512][64] -> [h][64][512]
        int idx = blk - 2048;
        int xx = idx & 7, yy = idx >> 3;
        int p = yy >> 3, h = yy & 7;
        const float* in = ((p == 0) ? wq : (p == 1) ? wk : wv) + (size_t)h * DMODEL * DK;
        unsigned short* out = ((p == 0) ? oq : (p == 1) ? ok : ov) + (size_t)h * DK * DMODEL;
        int r0 = xx * 64;
#pragma unroll
        for (int rr = 0; rr < 4; ++rr) {
            float4 v = *reinterpret_cast<const float4*>(in + (size_t)(r0 + tr + rr * 16) * DK + tc4);
            tile[tr + rr * 16][tc4 + 0] = v.x;
            tile[tr + rr * 16][tc4 + 1] = v.y;
            tile[tr + rr * 16][tc4 + 2] = v.z;
            tile[tr + rr * 16][tc4 + 3] = v.w;
        }
        __syncthreads();
#pragma unroll
        for (int rr = 0; rr < 4; ++rr) {
            const int c = tr + rr * 16;
            ushort4 o;
            o.x = f2bf(tile[tc4 + 0][c]);
            o.y = f2bf(tile[tc4 + 1][c]);
            o.z = f2bf(tile[tc4 + 2][c]);
            o.w = f2bf(tile[tc4 + 3][c]);
            *reinterpret_cast<ushort4*>(out + (size_t)c * DMODEL + r0 + tc4) = o;
        }
        return;
    }
    {  // wo: [512][512] -> transposed
        int idx = blk - 2240;
        int c0 = (idx & 7) * 64, r0 = (idx >> 3) * 64;
#pragma unroll
        for (int rr = 0; rr < 4; ++rr) {
            float4 v = *reinterpret_cast<const float4*>(wo + (size_t)(r0 + tr + rr * 16) * DMODEL + c0 + tc4);
            tile[tr + rr * 16][tc4 + 0] = v.x;
            tile[tr + rr * 16][tc4 + 1] = v.y;
            tile[tr + rr * 16][tc4 + 2] = v.z;
            tile[tr + rr * 16][tc4 + 3] = v.w;
        }
        __syncthreads();
#pragma unroll
        for (int rr = 0; rr < 4; ++rr) {
            const int c = tr + rr * 16;
            ushort4 o;
            o.x = f2bf(tile[tc4 + 0][c]);
            o.y = f2bf(tile[tc4 + 1][c]);
            o.z = f2bf(tile[tc4 + 2][c]);
            o.w = f2bf(tile[tc4 + 3][c]);
            *reinterpret_cast<ushort4*>(woT + (size_t)(c0 + c) * DMODEL + r0 + tc4) = o;
        }
    }
}

// ---------------- tiled QKV projection GEMM (m97 structure) ----------------
__global__ __launch_bounds__(256, 2) void proj_tiled_kernel(
    const unsigned short* __restrict__ A,
    const unsigned short* __restrict__ BTall,
    unsigned short* __restrict__ Qo,
    unsigned short* __restrict__ Ko,
    unsigned short* __restrict__ Vo) {
    __shared__ unsigned short lds[32768];
    const int tid = threadIdx.x;
    const int w = tid >> 6, l = tid & 63;
    const int l15 = l & 15, lg = l >> 4;
    const int wr = w >> 1, wc = w & 1;
    const int m0 = blockIdx.x * 128, n0 = blockIdx.y * 128;
    const int srow = l >> 3;
    const int schk = ((l & 7) ^ srow) << 3;
    f32x4 acc[4][4] = {};
    {
        unsigned short* ab = &lds[0];
        unsigned short* bb = &lds[8192];
#pragma unroll
        for (int g = 0; g < 4; ++g) {
            gload16(A + (size_t)(m0 + w * 32 + g * 8 + srow) * DMODEL + schk,
                    ab + (w * 32 + g * 8) * 64);
            gload16(BTall + (size_t)(n0 + w * 32 + g * 8 + srow) * DMODEL + schk,
                    bb + (w * 32 + g * 8) * 64);
        }
    }
    __syncthreads();
    for (int kt = 0; kt < 8; ++kt) {
        const int b = (kt & 1) * 16384;
        if (kt + 1 < 8) {
            const int nb = ((kt + 1) & 1) * 16384;
            const int k0 = (kt + 1) * 64;
            unsigned short* ab = &lds[nb];
            unsigned short* bb = &lds[nb + 8192];
#pragma unroll
            for (int g = 0; g < 4; ++g) {
                gload16(A + (size_t)(m0 + w * 32 + g * 8 + srow) * DMODEL + k0 + schk,
                        ab + (w * 32 + g * 8) * 64);
                gload16(BTall + (size_t)(n0 + w * 32 + g * 8 + srow) * DMODEL + k0 + schk,
                        bb + (w * 32 + g * 8) * 64);
            }
        }
#pragma unroll
        for (int kk = 0; kk < 2; ++kk) {
            short8 am[4], bn[4];
#pragma unroll
            for (int mi = 0; mi < 4; ++mi) {
                const int row = wr * 64 + mi * 16 + l15;
                am[mi] = *reinterpret_cast<const short8*>(
                    &lds[b + row * 64 + ((kk * 32 + lg * 8) ^ ((row & 7) << 3))]);
            }
#pragma unroll
            for (int ni = 0; ni < 4; ++ni) {
                const int row = wc * 64 + ni * 16 + l15;
                bn[ni] = *reinterpret_cast<const short8*>(
                    &lds[b + 8192 + row * 64 + ((kk * 32 + lg * 8) ^ ((row & 7) << 3))]);
            }
#pragma unroll
            for (int mi = 0; mi < 4; ++mi)
#pragma unroll
                for (int ni = 0; ni < 4; ++ni)
                    acc[mi][ni] = __builtin_amdgcn_mfma_f32_16x16x32_bf16(am[mi], bn[ni], acc[mi][ni], 0, 0, 0);
        }
        __syncthreads();
    }
#pragma unroll
    for (int ni = 0; ni < 4; ++ni) {
        const int n = n0 + wc * 64 + ni * 16;
        const int p = n >> 9, h = (n >> 6) & 7, vb = n & 63;
        unsigned short* dst = ((p == 0) ? Qo : (p == 1) ? Ko : Vo) + (size_t)h * S_LEN * DK;
        const float sc = (p == 0) ? QSCALE : 1.0f;
#pragma unroll
        for (int mi = 0; mi < 4; ++mi) {
            const int s = m0 + wr * 64 + mi * 16 + lg * 4;
#pragma unroll
            for (int r = 0; r < 4; ++r)
                dst[(size_t)(s + r) * DK + vb + l15] = f2bf(acc[mi][ni][r] * sc);
        }
    }
}

// ---------------- V transpose + k-permute: Vb[h][t][v] -> VTp[h][v][t'] -----
__global__ __launch_bounds__(256) void vt_kernel(const unsigned short* __restrict__ Vb,
                                                 unsigned short* __restrict__ VT) {
    __shared__ unsigned short tile[4096];
    int h = blockIdx.y, t0 = blockIdx.x * 64;
    const unsigned short* Vh = Vb + h * (S_LEN * DK);
    unsigned short* VTh = VT + h * (DK * S_LEN);
    int c8 = (threadIdx.x & 7) * 8, rw = threadIdx.x >> 3;
#pragma unroll
    for (int rr = 0; rr < 2; ++rr) {
        int t = rw + rr * 32;
        short8 v = *reinterpret_cast<const short8*>(Vh + (t0 + t) * DK + c8);
        *reinterpret_cast<short8*>(&tile[t * 64 + (c8 ^ ((t & 7) << 3))]) = v;
    }
    __syncthreads();
    const int g16 = c8 & ~15;
    const int h4 = (c8 & 8) ? 4 : 0;
#pragma unroll
    for (int rr = 0; rr < 2; ++rr) {
        int v = rw + rr * 32;
        short8 s;
#pragma unroll
        for (int i = 0; i < 8; ++i) {
            int t = g16 + h4 + ((i < 4) ? i : (i + 4));  // k-permuted source
            s[i] = (short)tile[t * 64 + (v ^ ((t & 7) << 3))];
        }
        *reinterpret_cast<short8*>(VTh + v * S_LEN + t0 + c8) = s;
    }
}

// ---------------- fused attention (unnormalized, split over t) ----------------
// Best-measured structure (r18): 2-buf, one barrier/tile, hoisted bv reads,
// interleaved pfrag(s0) -> PV(qc0) -> pfrag(s1) -> PV(qc1).
__device__ __forceinline__ void make_pfrag(const f32x16& s, short8 pf[2],
                                           float& z0, float& z1) {
    float p[16];
#pragma unroll
    for (int r = 0; r < 16; ++r) p[r] = EXPFN(s[r]);
#pragma unroll
    for (int r = 0; r < 16; r += 2) { z0 += p[r]; z1 += p[r + 1]; }
    unsigned int c[8];
#pragma unroll
    for (int j = 0; j < 8; ++j)
        asm("v_cvt_pk_bf16_f32 %0, %1, %2" : "=v"(c[j]) : "v"(p[2 * j]), "v"(p[2 * j + 1]));
    uint4v wa = {c[0], c[1], c[2], c[3]};
    uint4v wb = {c[4], c[5], c[6], c[7]};
    pf[0] = __builtin_bit_cast(short8, wa);
    pf[1] = __builtin_bit_cast(short8, wb);
}

__global__ __launch_bounds__(256, 2) void attn_kernel(
    const unsigned short* __restrict__ Qg,
    const unsigned short* __restrict__ Kg,
    const unsigned short* __restrict__ VTg,
    unsigned short* __restrict__ Opart,
    float* __restrict__ Z) {
    __shared__ unsigned short lds[16384];  // 2 bufs x (K[64][64] + VT[64][64]) = 32KB
    const int tid = threadIdx.x;
    const int w = tid >> 6, l = tid & 63;
    const int l31 = l & 31, lh = l >> 5;
    const int vx = l31 & 7;
    const int qb = blockIdx.x, h = blockIdx.y, sp = blockIdx.z;
    const unsigned short* Qh = Qg + h * (S_LEN * DK);
    const unsigned short* Kh = Kg + h * (S_LEN * DK);
    const unsigned short* VTh = VTg + h * (DK * S_LEN);
    const int t_base = sp * (S_LEN / SPLIT);
    const int q0 = qb * 256 + w * 64;

    short8 bq[2][4];
#pragma unroll
    for (int qc = 0; qc < 2; ++qc)
#pragma unroll
        for (int ks = 0; ks < 4; ++ks)
            bq[qc][ks] = *reinterpret_cast<const short8*>(
                Qh + (q0 + qc * 32 + l31) * DK + ks * 16 + lh * 8);

    f32x16 oacc[2][2] = {};  // [qc][vc]
    float z0 = 0.0f, z1 = 0.0f;

    const int srow = l >> 3;
    const int scol = ((l & 7) ^ srow) << 3;
    const unsigned short* gk = Kh + (size_t)(t_base + w * 16 + srow) * DK + scol;
    const unsigned short* gv0 = VTh + (size_t)(w * 16 + srow) * S_LEN + t_base + scol;
    const unsigned short* gv1 = gv0 + 8 * S_LEN;

    {   // stage tile 0 -> buf 0
        unsigned short* kb = &lds[w * 1024];
        gload16(gk, kb);
        gload16(gk + 512, kb + 512);
        unsigned short* vb = &lds[4096 + w * 1024];
        gload16(gv0, vb);
        gload16(gv1, vb + 512);
        gk += 64 * DK; gv0 += 64; gv1 += 64;
    }
    __syncthreads();

    for (int it = 0; it < NT; ++it) {
        const int b = (it & 1) * 8192;
        if (it + 1 < NT) {  // async loads into other buf; drain at loop-end barrier
            const int nb = ((it + 1) & 1) * 8192;
            unsigned short* kb = &lds[nb + w * 1024];
            gload16(gk, kb);
            gload16(gk + 512, kb + 512);
            unsigned short* vb = &lds[nb + 4096 + w * 1024];
            gload16(gv0, vb);
            gload16(gv1, vb + 512);
            gk += 64 * DK; gv0 += 64; gv1 += 64;
        }
#pragma unroll
        for (int tc = 0; tc < 2; ++tc) {
            f32x16 s0 = {}, s1 = {};
            const int tA = tc * 32 + l31;
            __builtin_amdgcn_s_setprio(1);
#pragma unroll
            for (int ks = 0; ks < 4; ++ks) {
                short8 ka = *reinterpret_cast<const short8*>(
                    &lds[b + tA * 64 + ((ks * 16 + lh * 8) ^ ((tA & 7) << 3))]);
                s0 = __builtin_amdgcn_mfma_f32_32x32x16_bf16(ka, bq[0][ks], s0, 0, 0, 0);
                s1 = __builtin_amdgcn_mfma_f32_32x32x16_bf16(ka, bq[1][ks], s1, 0, 0, 0);
            }
            __builtin_amdgcn_s_setprio(0);
            // hoist PV B-frag reads (independent of exp): latency hides under exp
            short8 bv[2][2];
#pragma unroll
            for (int sub = 0; sub < 2; ++sub) {
                const int chk = (tc * 2 + sub) * 2 + lh;
#pragma unroll
                for (int vc = 0; vc < 2; ++vc) {
                    const int v = vc * 32 + l31;
                    bv[sub][vc] = *reinterpret_cast<const short8*>(
                        &lds[b + 4096 + v * 64 + ((chk ^ vx) << 3)]);
                }
            }
            // interleave: pfrag(s0) -> PV(qc0) while pfrag(s1) runs -> PV(qc1)
            short8 pf0[2], pf1[2];
            make_pfrag(s0, pf0, z0, z1);
#pragma unroll
            for (int sub = 0; sub < 2; ++sub)
#pragma unroll
                for (int vc = 0; vc < 2; ++vc)
                    oacc[0][vc] = __builtin_amdgcn_mfma_f32_32x32x16_bf16(pf0[sub], bv[sub][vc], oacc[0][vc], 0, 0, 0);
            make_pfrag(s1, pf1, z0, z1);
            __builtin_amdgcn_s_setprio(1);
#pragma unroll
            for (int sub = 0; sub < 2; ++sub)
#pragma unroll
                for (int vc = 0; vc < 2; ++vc)
                    oacc[1][vc] = __builtin_amdgcn_mfma_f32_32x32x16_bf16(pf1[sub], bv[sub][vc], oacc[1][vc], 0, 0, 0);
            __builtin_amdgcn_s_setprio(0);
        }
        __syncthreads();
    }
    // bf16 partials: Opart[sp][h][q][v], coalesced (lanes = consecutive v)
    unsigned short* Op = Opart + ((size_t)(sp * NHEAD + h) * S_LEN + q0) * DK;
#pragma unroll
    for (int qc = 0; qc < 2; ++qc)
#pragma unroll
        for (int vc = 0; vc < 2; ++vc)
#pragma unroll
            for (int reg = 0; reg < 16; ++reg) {
                int q = qc * 32 + (reg & 3) + 8 * (reg >> 2) + 4 * lh;
                Op[(size_t)q * DK + vc * 32 + l31] = f2bf(oacc[qc][vc][reg]);
            }
    float zloc = z0 + z1;
#pragma unroll
    for (int off = 32; off > 0; off >>= 1) zloc += __shfl_xor(zloc, off, 64);
    if (l == 0) atomicAdd(Z, zloc);
}

// ---------------- split reduction: sum bf16 partials -> bf16 concat ----------------
__global__ __launch_bounds__(256) void reduce_o_kernel(
    const unsigned short* __restrict__ Opart, unsigned short* __restrict__ cc) {
    const int HSV = NHEAD * S_LEN * DK;
    int i = blockIdx.x * blockDim.x + threadIdx.x;
    if (i * 4 >= HSV) return;
    float s0 = 0, s1 = 0, s2 = 0, s3 = 0;
#pragma unroll
    for (int sp = 0; sp < SPLIT; ++sp) {
        ushort4 v = *reinterpret_cast<const ushort4*>(&Opart[(size_t)sp * HSV + i * 4]);
        s0 += __uint_as_float((unsigned int)v.x << 16);
        s1 += __uint_as_float((unsigned int)v.y << 16);
        s2 += __uint_as_float((unsigned int)v.z << 16);
        s3 += __uint_as_float((unsigned int)v.w << 16);
    }
    int e = i * 4;
    int h = e / (S_LEN * DK);
    int rem = e - h * (S_LEN * DK);
    int srow = rem / DK;
    int v = rem - srow * DK;
    ushort4 o4;
    o4.x = f2bf(s0); o4.y = f2bf(s1); o4.z = f2bf(s2); o4.w = f2bf(s3);
    *reinterpret_cast<ushort4*>(&cc[srow * DMODEL + h * DK + v]) = o4;
}

// ---------------- tiled output projection GEMM (x 1/Z) ----------------
__global__ __launch_bounds__(256, 2) void out_tiled_kernel(
    const unsigned short* __restrict__ A,
    const unsigned short* __restrict__ BT,
    const float* __restrict__ Z,
    float* __restrict__ Cout) {
    __shared__ unsigned short lds[32768];
    const int tid = threadIdx.x;
    const int w = tid >> 6, l = tid & 63;
    const int l15 = l & 15, lg = l >> 4;
    const int wr = w >> 1, wc = w & 1;
    const int m0 = blockIdx.x * 128, n0 = blockIdx.y * 128;
    const int srow = l >> 3;
    const int schk = ((l & 7) ^ srow) << 3;
    const float invZ = 1.0f / *Z;
    f32x4 acc[4][4] = {};
    {
        unsigned short* ab = &lds[0];
        unsigned short* bb = &lds[8192];
#pragma unroll
        for (int g = 0; g < 4; ++g) {
            gload16(A + (size_t)(m0 + w * 32 + g * 8 + srow) * DMODEL + schk,
                    ab + (w * 32 + g * 8) * 64);
            gload16(BT + (size_t)(n0 + w * 32 + g * 8 + srow) * DMODEL + schk,
                    bb + (w * 32 + g * 8) * 64);
        }
    }
    __syncthreads();
    for (int kt = 0; kt < 8; ++kt) {
        const int b = (kt & 1) * 16384;
        if (kt + 1 < 8) {
            const int nb = ((kt + 1) & 1) * 16384;
            const int k0 = (kt + 1) * 64;
            unsigned short* ab = &lds[nb];
            unsigned short* bb = &lds[nb + 8192];
#pragma unroll
            for (int g = 0; g < 4; ++g) {
                gload16(A + (size_t)(m0 + w * 32 + g * 8 + srow) * DMODEL + k0 + schk,
                        ab + (w * 32 + g * 8) * 64);
                gload16(BT + (size_t)(n0 + w * 32 + g * 8 + srow) * DMODEL + k0 + schk,
                        bb + (w * 32 + g * 8) * 64);
            }
        }
#pragma unroll
        for (int kk = 0; kk < 2; ++kk) {
            short8 am[4], bn[4];
#pragma unroll
            for (int mi = 0; mi < 4; ++mi) {
                const int row = wr * 64 + mi * 16 + l15;
                am[mi] = *reinterpret_cast<const short8*>(
                    &lds[b + row * 64 + ((kk * 32 + lg * 8) ^ ((row & 7) << 3))]);
            }
#pragma unroll
            for (int ni = 0; ni < 4; ++ni) {
                const int row = wc * 64 + ni * 16 + l15;
                bn[ni] = *reinterpret_cast<const short8*>(
                    &lds[b + 8192 + row * 64 + ((kk * 32 + lg * 8) ^ ((row & 7) << 3))]);
            }
#pragma unroll
            for (int mi = 0; mi < 4; ++mi)
#pragma unroll
                for (int ni = 0; ni < 4; ++ni)
                    acc[mi][ni] = __builtin_amdgcn_mfma_f32_16x16x32_bf16(am[mi], bn[ni], acc[mi][ni], 0, 0, 0);
        }
        __syncthreads();
    }
#pragma unroll
    for (int ni = 0; ni < 4; ++ni) {
        const int n = n0 + wc * 64 + ni * 16;
#pragma unroll
        for (int mi = 0; mi < 4; ++mi) {
            const int s = m0 + wr * 64 + mi * 16 + lg * 4;
#pragma unroll
            for (int r = 0; r < 4; ++r)
                Cout[(size_t)(s + r) * DMODEL + n + l15] = acc[mi][ni][r] * invZ;
        }
    }
}

// ---------------- launcher ----------------

extern "C" void kernel_launch(void* const* d_in, const int* in_sizes, int n_in,
                              void* d_out, int out_size, void* d_ws, size_t ws_size,
                              hipStream_t stream) {
    const float* emb = (const float*)d_in[0];
    const float* wq = (const float*)d_in[1];
    const float* wk = (const float*)d_in[2];
    const float* wv = (const float*)d_in[3];
    const float* wo = (const float*)d_in[4];
    float* out = (float*)d_out;
    char* ws = (char*)d_ws;
    unsigned short* embB = (unsigned short*)(ws);             // 4 MB (reused as VT)
    unsigned short* wqT  = (unsigned short*)(ws + 4194304);   // contiguous 3 x 512 KB
    unsigned short* wkT  = (unsigned short*)(ws + 4718592);
    unsigned short* wvT  = (unsigned short*)(ws + 5242880);
    unsigned short* woT  = (unsigned short*)(ws + 5767168);
    unsigned short* Qb   = (unsigned short*)(ws + 6291456);   // 4 MB each
    unsigned short* Kb   = (unsigned short*)(ws + 10485760);
    unsigned short* Vb   = (unsigned short*)(ws + 14680064);
    unsigned short* cc   = (unsigned short*)(ws + 18874368);  // 4 MB
    float* Z             = (float*)(ws + 23068672);
    unsigned short* Opart = (unsigned short*)(ws + 23072768); // 16 MB (4 x 4 MB bf16)
    unsigned short* VT   = embB;  // embB dead after proj

    prep_kernel<<<2304, 256, 0, stream>>>(emb, wq, wk, wv, wo, embB, wqT, wkT, wvT, woT, Z);
    proj_tiled_kernel<<<dim3(32, 12), 256, 0, stream>>>(embB, wqT, Qb, Kb, Vb);
    vt_kernel<<<dim3(64, 8), 256, 0, stream>>>(Vb, VT);
    attn_kernel<<<dim3(16, 8, SPLIT), 256, 0, stream>>>(Qb, Kb, VT, Opart, Z);
    reduce_o_kernel<<<2048, 256, 0, stream>>>(Opart, cc);
    out_tiled_kernel<<<dim3(32, 4), 256, 0, stream>>>(cc, woT, Z, out);
}